// Round 1
// baseline (185.492 us; speedup 1.0000x reference)
//
#include <hip/hip_runtime.h>
#include <float.h>
#include <math.h>

#define HH   64
#define PW   66      // padded LDS row stride (zero border, no edge branches in loop)
#define NQ   10
#define NHID 150

__global__ __launch_bounds__(1024) void vin_kernel(
    const float* __restrict__ input,     // (B,2,64,64)
    const int*   __restrict__ state_x,   // (B)
    const int*   __restrict__ state_y,   // (B)
    const int*   __restrict__ num_vi_p,  // (1)
    const float* __restrict__ W_h,       // (150,2,3,3)
    const float* __restrict__ b_h,       // (150)
    const float* __restrict__ W_r,       // (150)  [shape (1,150,1,1)]
    const float* __restrict__ W_q,       // (10,1,3,3)
    const float* __restrict__ W_v,       // (10,1,3,3)
    const float* __restrict__ W_fc,      // (8,10)
    float*       __restrict__ out)       // logits (128,8) ++ softmax (128,8)
{
    __shared__ float rbuf[PW * PW];
    __shared__ float vbuf[PW * PW];
    __shared__ float weff[20];           // 18 collapsed weights + b_eff
    __shared__ float wq[NQ * 9];
    __shared__ float wv[NQ * 9];

    const int b   = blockIdx.x;
    const int t   = threadIdx.x;
    const int col = t & 63;              // 0..63
    const int rb  = (t >> 6) << 2;       // row base 0,4,...,60 (4 rows/thread)

    // zero padded buffers (border must be 0 for pad=1 convs)
    for (int i = t; i < PW * PW; i += 1024) { rbuf[i] = 0.f; vbuf[i] = 0.f; }

    // collapse hidden layer: W_eff = sum_c W_r[c]*W_h[c], b_eff = sum_c W_r[c]*b_h[c]
    if (t < 18) {
        float s = 0.f;
        for (int c = 0; c < NHID; ++c) s += W_r[c] * W_h[c * 18 + t];
        weff[t] = s;
    } else if (t == 18) {
        float s = 0.f;
        for (int c = 0; c < NHID; ++c) s += W_r[c] * b_h[c];
        weff[18] = s;
    }
    if (t >= 64  && t < 64  + NQ * 9) wq[t - 64]  = W_q[t - 64];
    if (t >= 192 && t < 192 + NQ * 9) wv[t - 192] = W_v[t - 192];
    __syncthreads();

    // ---- reward = conv3x3(input, W_eff) + b_eff  -> rbuf (padded) ----
    {
        const float beff = weff[18];
        const float* ip0 = input + (size_t)b * 2 * HH * HH;
        const float* ip1 = ip0 + HH * HH;
        #pragma unroll
        for (int p = 0; p < 4; ++p) {
            const int r = rb + p;
            float s = beff;
            #pragma unroll
            for (int kh = 0; kh < 3; ++kh) {
                const int rr = r + kh - 1;
                if (rr < 0 || rr >= HH) continue;
                #pragma unroll
                for (int kw = 0; kw < 3; ++kw) {
                    const int cc = col + kw - 1;
                    if (cc < 0 || cc >= HH) continue;
                    s += weff[kh * 3 + kw]     * ip0[rr * HH + cc];
                    s += weff[9 + kh * 3 + kw] * ip1[rr * HH + cc];
                }
            }
            rbuf[(r + 1) * PW + col + 1] = s;
        }
    }
    __syncthreads();

    // ---- qr[i] = conv3x3(reward, W_q[i]) (iteration-invariant), v0 = max_i qr ----
    float qr[NQ][4];
    {
        float n[6][3];
        #pragma unroll
        for (int i = 0; i < 6; ++i)
            #pragma unroll
            for (int j = 0; j < 3; ++j)
                n[i][j] = rbuf[(rb + i) * PW + col + j];

        float vcur[4];
        #pragma unroll
        for (int p = 0; p < 4; ++p) vcur[p] = -FLT_MAX;

        #pragma unroll
        for (int i = 0; i < NQ; ++i) {
            float s[4] = {0.f, 0.f, 0.f, 0.f};
            #pragma unroll
            for (int kh = 0; kh < 3; ++kh)
                #pragma unroll
                for (int kw = 0; kw < 3; ++kw) {
                    const float w = wq[i * 9 + kh * 3 + kw];
                    #pragma unroll
                    for (int p = 0; p < 4; ++p) s[p] += w * n[p + kh][kw];
                }
            #pragma unroll
            for (int p = 0; p < 4; ++p) {
                qr[i][p] = s[p];
                vcur[p]  = fmaxf(vcur[p], s[p]);
            }
        }
        #pragma unroll
        for (int p = 0; p < 4; ++p)
            vbuf[(rb + p + 1) * PW + col + 1] = vcur[p];
    }
    __syncthreads();

    // ---- VI loop: v = max_i (qr[i] + conv3x3(v, W_v[i])) ----
    const int niter = num_vi_p[0] - 1;
    for (int it = 0; it < niter; ++it) {
        float n[6][3];
        #pragma unroll
        for (int i = 0; i < 6; ++i)
            #pragma unroll
            for (int j = 0; j < 3; ++j)
                n[i][j] = vbuf[(rb + i) * PW + col + j];

        float vnew[4];
        #pragma unroll
        for (int p = 0; p < 4; ++p) vnew[p] = -FLT_MAX;

        #pragma unroll
        for (int i = 0; i < NQ; ++i) {
            float s[4] = {qr[i][0], qr[i][1], qr[i][2], qr[i][3]};
            #pragma unroll
            for (int kh = 0; kh < 3; ++kh)
                #pragma unroll
                for (int kw = 0; kw < 3; ++kw) {
                    const float w = wv[i * 9 + kh * 3 + kw];
                    #pragma unroll
                    for (int p = 0; p < 4; ++p) s[p] += w * n[p + kh][kw];
                }
            #pragma unroll
            for (int p = 0; p < 4; ++p) vnew[p] = fmaxf(vnew[p], s[p]);
        }
        __syncthreads();                  // all reads of old v complete
        #pragma unroll
        for (int p = 0; p < 4; ++p)
            vbuf[(rb + p + 1) * PW + col + 1] = vnew[p];
        __syncthreads();                  // new v visible to all
    }

    // ---- final gather at (state_x, state_y) + FC + softmax, one thread/block ----
    const int sx = state_x[b];
    const int sy = state_y[b];
    if (col == sy && (sx >> 2) == (rb >> 2)) {
        const int p = sx & 3;
        // runtime p: select with compile-time-indexed reads (avoid scratch, rule #20)
        float qp[NQ];
        #pragma unroll
        for (int i = 0; i < NQ; ++i) {
            const float lo = (p & 1) ? qr[i][1] : qr[i][0];
            const float hi = (p & 1) ? qr[i][3] : qr[i][2];
            qp[i] = (p & 2) ? hi : lo;
        }
        float qxy[NQ];
        #pragma unroll
        for (int i = 0; i < NQ; ++i) {
            float s = qp[i];
            #pragma unroll
            for (int kh = 0; kh < 3; ++kh)
                #pragma unroll
                for (int kw = 0; kw < 3; ++kw)
                    s += wv[i * 9 + kh * 3 + kw] * vbuf[(sx + kh) * PW + sy + kw];
            qxy[i] = s;
        }
        float logits[8];
        float m = -FLT_MAX;
        #pragma unroll
        for (int j = 0; j < 8; ++j) {
            float s = 0.f;
            #pragma unroll
            for (int i = 0; i < NQ; ++i) s += W_fc[j * NQ + i] * qxy[i];
            logits[j] = s;
            m = fmaxf(m, s);
        }
        float e[8];
        float esum = 0.f;
        #pragma unroll
        for (int j = 0; j < 8; ++j) { e[j] = expf(logits[j] - m); esum += e[j]; }
        const float inv = 1.f / esum;
        #pragma unroll
        for (int j = 0; j < 8; ++j) {
            out[b * 8 + j]           = logits[j];
            out[128 * 8 + b * 8 + j] = e[j] * inv;
        }
    }
}

extern "C" void kernel_launch(void* const* d_in, const int* in_sizes, int n_in,
                              void* d_out, int out_size, void* d_ws, size_t ws_size,
                              hipStream_t stream) {
    const float* input   = (const float*)d_in[0];
    const int*   sx      = (const int*)  d_in[1];
    const int*   sy      = (const int*)  d_in[2];
    const int*   num_vi  = (const int*)  d_in[3];
    const float* W_h     = (const float*)d_in[4];
    const float* b_h     = (const float*)d_in[5];
    const float* W_r     = (const float*)d_in[6];
    const float* W_q     = (const float*)d_in[7];
    const float* W_v     = (const float*)d_in[8];
    const float* W_fc    = (const float*)d_in[9];
    float* out = (float*)d_out;

    const int B = in_sizes[1];   // 128
    vin_kernel<<<dim3(B), dim3(1024), 0, stream>>>(
        input, sx, sy, num_vi, W_h, b_h, W_r, W_q, W_v, W_fc, out);
}